// Round 2
// baseline (2831.370 us; speedup 1.0000x reference)
//
#include <hip/hip_runtime.h>
#include <hip/hip_bf16.h>

#define NT 1024
#define NNODES 4096
#define ECAP 65536   // max arcs after iteration-1 symmetrization (E0 <= 32768)

// ---------------- block-wide exclusive scan over NT=1024 values ----------------
__device__ __forceinline__ int blockScanExcl(int v, int* s_w, int* total) {
    const int tid  = threadIdx.x;
    const int lane = tid & 63;
    const int wv   = tid >> 6;
    int x = v;
#pragma unroll
    for (int off = 1; off < 64; off <<= 1) {
        int t = __shfl_up(x, off, 64);
        if (lane >= off) x += t;
    }
    if (lane == 63) s_w[wv] = x;
    __syncthreads();
    if (tid < 16) {
        int y = s_w[tid];
#pragma unroll
        for (int off = 1; off < 16; off <<= 1) {
            int t = __shfl_up(y, off, 16);
            if (tid >= off) y += t;
        }
        s_w[tid] = y;
    }
    __syncthreads();
    int base = wv ? s_w[wv - 1] : 0;
    int tot  = s_w[15];
    __syncthreads();   // protect s_w reuse
    *total = tot;
    return base + x - v;   // exclusive prefix
}

// ---------------- Phase A: full coarsening, single block ----------------
// s_bc slots: 0=node 1=p 2=nbrCnt 3=hnCnt 4=orderBase 5=appendBase 6=finalBase 7=maxdeg 9=not64
__global__ __launch_bounds__(NT, 1)
void phaseA(const int* __restrict__ ei, int E0,
            int* __restrict__ U, int* __restrict__ V,
            unsigned int* __restrict__ BM,
            int* __restrict__ SLOT, int* __restrict__ NBR,
            int* __restrict__ SEL, int* __restrict__ CNTS,
            int* __restrict__ NST, int* __restrict__ FIL, int* __restrict__ SC,
            float* __restrict__ out)
{
    __shared__ unsigned short s_order[NNODES];
    __shared__ unsigned char  s_vis[NNODES];
    __shared__ unsigned char  s_sel[NNODES];
    __shared__ unsigned int   s_hb[NNODES / 32];
    __shared__ unsigned short s_so[NNODES];     // selection order
    __shared__ unsigned short s_cnt[NNODES];    // counts per hub
    __shared__ unsigned int   s_nst[NNODES];    // nbr segment starts
    __shared__ int s_roff[NNODES];              // CSR row start
    __shared__ int s_rend[NNODES];              // CSR row end
    __shared__ int s_tmp[NNODES];               // deg / iter-0 stage / HnList / rank
    __shared__ int s_w[16];
    __shared__ int s_bc[16];

    const int tid = threadIdx.x;

    for (int i = tid; i < NNODES; i += NT) { s_vis[i] = 0; s_sel[i] = 0; s_tmp[i] = 0; }
    for (int i = tid; i < NNODES / 32; i += NT) s_hb[i] = 0;
    if (tid < 16) s_bc[tid] = 0;
    __syncthreads();

    // ---- detect int64 vs int32 edge buffer (high words all zero => int64) ----
    for (int i = tid; i < E0; i += NT)
        if (ei[2 * i + 1] != 0) s_bc[9] = 1;
    __syncthreads();
    const int is64 = !s_bc[9];

    // ---- copy edges + degree histogram (I+O) ----
    for (int e = tid; e < E0; e += NT) {
        int uu = ei[is64 ? 2 * e : e];
        int vv = ei[is64 ? 2 * (E0 + e) : (E0 + e)];
        U[e] = uu; V[e] = vv;
        atomicAdd(&s_tmp[uu], 1);
        atomicAdd(&s_tmp[vv], 1);
    }
    __syncthreads();
    for (int n = tid; n < NNODES; n += NT) atomicMax(&s_bc[7], s_tmp[n]);
    __syncthreads();
    const int maxd = s_bc[7];

    // ---- stable argsort by descending degree (counting placement) ----
    for (int d = maxd; d >= 0; --d) {
        int n0 = tid * 4;
        int f0 = (s_tmp[n0] == d), f1 = (s_tmp[n0 + 1] == d);
        int f2 = (s_tmp[n0 + 2] == d), f3 = (s_tmp[n0 + 3] == d);
        int tot;
        int off = blockScanExcl(f0 + f1 + f2 + f3, s_w, &tot);
        int idx = s_bc[4] + off;
        if (f0) s_order[idx++] = (unsigned short)n0;
        if (f1) s_order[idx++] = (unsigned short)(n0 + 1);
        if (f2) s_order[idx++] = (unsigned short)(n0 + 2);
        if (f3) s_order[idx++] = (unsigned short)(n0 + 3);
        __syncthreads();
        if (tid == 0) s_bc[4] += tot;
        __syncthreads();
    }

    // ================= iteration 0 (full-array scans) =================
    if (tid == 0) {
        int nd = s_order[0];
        s_bc[0] = nd; s_sel[nd] = 1; s_vis[nd] = 1;
        s_so[0] = (unsigned short)nd; s_nst[0] = 0;
    }
    __syncthreads();
    {
        const int node = s_bc[0];
        for (int e = tid; e < E0; e += NT) {
            int uu = U[e], vv = V[e];
            if (uu == node) {
                int w = vv; unsigned m = 1u << (w & 31);
                unsigned old = atomicOr(&s_hb[w >> 5], m);
                if (!(old & m)) { int i = atomicAdd(&s_bc[2], 1); s_tmp[i] = w; s_vis[w] = 1; }
            }
            if (vv == node) {
                int w = uu; unsigned m = 1u << (w & 31);
                unsigned old = atomicOr(&s_hb[w >> 5], m);
                if (!(old & m)) { int i = atomicAdd(&s_bc[2], 1); s_tmp[i] = w; s_vis[w] = 1; }
            }
        }
        __syncthreads();
        if (tid == 0) s_cnt[0] = (unsigned short)s_bc[2];
        // relabel Hn = H \ {node}
        for (int e = tid; e < E0; e += NT) {
            int uu = U[e];
            if (uu != node && ((s_hb[uu >> 5] >> (uu & 31)) & 1)) U[e] = node;
            int vv = V[e];
            if (vv != node && ((s_hb[vv >> 5] >> (vv & 31)) & 1)) V[e] = node;
        }
        __syncthreads();
    }

    // ---- symmetry append (only iteration ever needing it) ----
    for (int i = tid; i < (1 << 19); i += NT) BM[i] = 0u;
    __syncthreads();
    for (int e = tid; e < E0; e += NT) {
        int uu = U[e], vv = V[e];
        if (uu != vv) {
            unsigned code = ((unsigned)uu << 12) | (unsigned)vv;
            atomicOr(&BM[code >> 5], 1u << (code & 31));
        }
    }
    __syncthreads();
    for (int t = 0; t < E0; t += NT) {
        int e = t + tid, flag = 0, uu = 0, vv = 0;
        if (e < E0) {
            uu = U[e]; vv = V[e];
            if (uu != vv) {
                unsigned rc = ((unsigned)vv << 12) | (unsigned)uu;
                unsigned old = atomicOr(&BM[rc >> 5], 0u);   // L2 read (bypasses stale L1)
                flag = !((old >> (rc & 31)) & 1u);
            }
        }
        int tot;
        int off = blockScanExcl(flag, s_w, &tot);
        if (flag) { int r = s_bc[5] + off; U[E0 + r] = vv; V[E0 + r] = uu; }
        __syncthreads();
        if (tid == 0) s_bc[5] += tot;
        __syncthreads();
    }
    const int E1 = E0 + s_bc[5];

    // ---- build static CSR over alive arcs (bitmap region now reused as SLOT/NBR) ----
    for (int n = tid; n < NNODES; n += NT) s_roff[n] = 0;
    __syncthreads();
    for (int e = tid; e < E1; e += NT) {
        int uu = U[e], vv = V[e];
        if (uu != vv) { atomicAdd(&s_roff[uu], 1); atomicAdd(&s_roff[vv], 1); }
    }
    __syncthreads();
    {
        int n0 = tid * 4;
        int c0 = s_roff[n0], c1 = s_roff[n0 + 1], c2 = s_roff[n0 + 2], c3 = s_roff[n0 + 3];
        int tot;
        int off = blockScanExcl(c0 + c1 + c2 + c3, s_w, &tot);
        int st = off;
        s_roff[n0] = st;     s_rend[n0] = st;     st += c0;
        s_roff[n0 + 1] = st; s_rend[n0 + 1] = st; st += c1;
        s_roff[n0 + 2] = st; s_rend[n0 + 2] = st; st += c2;
        s_roff[n0 + 3] = st; s_rend[n0 + 3] = st;
    }
    __syncthreads();
    for (int e = tid; e < E1; e += NT) {
        int uu = U[e], vv = V[e];
        if (uu != vv) {
            int p = atomicAdd(&s_rend[uu], 1); SLOT[p] = 2 * e;
            p = atomicAdd(&s_rend[vv], 1);     SLOT[p] = 2 * e + 1;
        }
    }
    __syncthreads();
    {   // flush iter-0 staged H into global NBR; reset bitset
        const int cnt0 = s_bc[2];
        for (int i = tid; i < cnt0; i += NT) NBR[i] = s_tmp[i];
    }
    for (int i = tid; i < NNODES / 32; i += NT) s_hb[i] = 0;
    __syncthreads();

    // ================= main loop: CSR-driven iterations =================
    int k = 1;
    for (;;) {
        if (tid == 0) {
            s_bc[3] = 0;                       // hnCnt
            int p = s_bc[1];
            while (p < NNODES && s_vis[s_order[p]]) p++;
            s_bc[1] = p;
            if (p < NNODES) {
                int nd = s_order[p];
                s_bc[0] = nd; s_sel[nd] = 1; s_vis[nd] = 1;
                s_so[k] = (unsigned short)nd;
                s_nst[k] = (unsigned)s_bc[2];
            }
        }
        __syncthreads();
        if (s_bc[1] >= NNODES) break;
        const int node = s_bc[0];
        const int rb = s_roff[node], re = s_rend[node];
        for (int s = rb + tid; s < re; s += NT) {
            int sl = SLOT[s]; int e = sl >> 1;
            int w = (sl & 1) ? U[e] : V[e];
            unsigned m = 1u << (w & 31);
            unsigned old = atomicOr(&s_hb[w >> 5], m);
            if (!(old & m)) {
                int i = atomicAdd(&s_bc[2], 1); NBR[i] = w; s_vis[w] = 1;
                if (!s_sel[w]) { int j = atomicAdd(&s_bc[3], 1); s_tmp[j] = w; }
            }
        }
        __syncthreads();
        if (tid == 0) s_cnt[k] = (unsigned short)(s_bc[2] - (int)s_nst[k]);
        const int hn = s_bc[3];
        for (int i = tid; i < hn; i += NT) {
            int h = s_tmp[i];
            int e0 = s_roff[h], e1 = s_rend[h];
            for (int s = e0; s < e1; ++s) {
                int sl = SLOT[s]; int e = sl >> 1;
                if (sl & 1) V[e] = node; else U[e] = node;
            }
        }
        for (int i = tid; i < NNODES / 32; i += NT) s_hb[i] = 0;
        __syncthreads();
        k++;
    }
    const int K = k;

    // ---- dump metadata ----
    for (int i = tid; i < K; i += NT) {
        SEL[i] = (int)s_so[i]; CNTS[i] = (int)s_cnt[i]; NST[i] = (int)s_nst[i];
    }
    if (tid == 0) {
        SC[0] = K;
        int f = 0;
        for (int i = 0; i < K; i++) { if (s_cnt[i] > 0) f = i; FIL[i] = f; }
    }
    // ---- rank of each selected node among sorted(select) ----
    {
        int n0 = tid * 4;
        int r0 = s_sel[n0], r1 = s_sel[n0 + 1], r2 = s_sel[n0 + 2], r3 = s_sel[n0 + 3];
        int tot;
        int off = blockScanExcl(r0 + r1 + r2 + r3, s_w, &tot);
        int st = off;
        s_tmp[n0] = st;     st += r0;
        s_tmp[n0 + 1] = st; st += r1;
        s_tmp[n0 + 2] = st; st += r2;
        s_tmp[n0 + 3] = st;
    }
    __syncthreads();
    // ---- final stable compaction + remap + write ei_out (float32) ----
    const size_t obase = (size_t)K * 8192;
    for (int t = 0; t < E1; t += NT) {
        int e = t + tid, flag = 0, uu = 0, vv = 0;
        if (e < E1) { uu = U[e]; vv = V[e]; flag = (uu != vv); }
        int tot;
        int off = blockScanExcl(flag, s_w, &tot);
        if (flag) {
            int r = s_bc[6] + off;
            out[obase + (size_t)r] = (float)s_tmp[uu];
            SLOT[r] = s_tmp[vv];
        }
        __syncthreads();
        if (tid == 0) s_bc[6] += tot;
        __syncthreads();
    }
    const int Ef = s_bc[6];
    if (tid == 0) SC[1] = Ef;
    for (int r = tid; r < Ef; r += NT)
        out[obase + (size_t)Ef + (size_t)r] = (float)SLOT[r];
}

// ---------------- Phase B: END rows (Dv | mean) with fill indirection ----------------
__global__ __launch_bounds__(256, 4)
void phaseB(const float* __restrict__ x,
            const float* __restrict__ W1, const float* __restrict__ W2,
            const float* __restrict__ B1, const float* __restrict__ B2,
            const int* __restrict__ NBR, const int* __restrict__ SEL,
            const int* __restrict__ CNTS, const int* __restrict__ NST,
            const int* __restrict__ FIL, const int* __restrict__ SC,
            float* __restrict__ out)
{
    const int K = SC[0];
    const int k = blockIdx.x;
    if (k >= K) return;
    const int kk   = FIL[k];
    const int node = SEL[kk];
    const int cnt  = CNTS[kk];
    const int st   = NST[kk];
    const int tid  = threadIdx.x;
    const float4* x4 = (const float4*)x;

    float4 acc[4];
#pragma unroll
    for (int j = 0; j < 4; j++) acc[j] = make_float4(0.f, 0.f, 0.f, 0.f);

    for (int r = 0; r < cnt; ++r) {
        const float4* row = x4 + (size_t)NBR[st + r] * 1024;
#pragma unroll
        for (int j = 0; j < 4; j++) {
            float4 t = row[tid + j * 256];
            acc[j].x += t.x; acc[j].y += t.y; acc[j].z += t.z; acc[j].w += t.w;
        }
    }

    const float fc  = (float)cnt;
    const float inv = 1.0f / (float)(cnt > 1 ? cnt : 1);
    const float4* xr = x4 + (size_t)node * 1024;
    float4* o4 = (float4*)(out + (size_t)k * 8192);

#pragma unroll
    for (int j = 0; j < 4; j++) {
        int c = tid + j * 256;
        float4 w1 = ((const float4*)W1)[c], b1 = ((const float4*)B1)[c];
        float4 w2 = ((const float4*)W2)[c], b2 = ((const float4*)B2)[c];
        float4 xv = xr[c];
        float4 pd, pm;
        pd.x = xv.x * w2.x + b2.x;
        pd.y = xv.y * w2.y + b2.y;
        pd.z = xv.z * w2.z + b2.z;
        pd.w = xv.w * w2.w + b2.w;
        pm.x = (acc[j].x * w1.x + fc * b1.x) * inv;
        pm.y = (acc[j].y * w1.y + fc * b1.y) * inv;
        pm.z = (acc[j].z * w1.z + fc * b1.z) * inv;
        pm.w = (acc[j].w * w1.w + fc * b1.w) * inv;
        o4[c] = pd;
        o4[1024 + c] = pm;
    }
}

extern "C" void kernel_launch(void* const* d_in, const int* in_sizes, int n_in,
                              void* d_out, int out_size, void* d_ws, size_t ws_size,
                              hipStream_t stream)
{
    const float* x  = (const float*)d_in[0];
    const int*   ei = (const int*)d_in[1];
    const float* W1 = (const float*)d_in[2];
    const float* W2 = (const float*)d_in[3];
    const float* B1 = (const float*)d_in[4];
    const float* B2 = (const float*)d_in[5];
    const int E0 = in_sizes[1] / 2;

    char* w = (char*)d_ws;
    int* U = (int*)w;                         // [ECAP]
    int* V = U + ECAP;                        // [ECAP]
    unsigned int* BM = (unsigned int*)(V + ECAP);   // 2 MB bitmap (iter-0 only)
    int* SLOT = (int*)BM;                     // [2*ECAP] (reuses bitmap region)
    int* NBR  = SLOT + 2 * ECAP;              // [2*ECAP] (reuses bitmap region)
    char* meta = (char*)BM + (2u << 20);
    int* SEL  = (int*)meta;
    int* CNTS = SEL + NNODES;
    int* NST  = CNTS + NNODES;
    int* FIL  = NST + NNODES;
    int* SC   = FIL + NNODES;
    float* out = (float*)d_out;

    hipLaunchKernelGGL(phaseA, dim3(1), dim3(NT), 0, stream,
                       ei, E0, U, V, BM, SLOT, NBR, SEL, CNTS, NST, FIL, SC, out);
    hipLaunchKernelGGL(phaseB, dim3(NNODES), dim3(256), 0, stream,
                       x, W1, W2, B1, B2, NBR, SEL, CNTS, NST, FIL, SC, out);
}

// Round 3
// 1750.844 us; speedup vs baseline: 1.6171x; 1.6171x over previous
//
#include <hip/hip_runtime.h>
#include <hip/hip_bf16.h>

#define NT 1024
#define NNODES 4096
#define ECAP 65536   // max arcs after iteration-1 symmetrization (E0 <= 32768)

// ---------------- block-wide exclusive scan over NT=1024 values ----------------
__device__ __forceinline__ int blockScanExcl(int v, int* s_w, int* total) {
    const int tid  = threadIdx.x;
    const int lane = tid & 63;
    const int wv   = tid >> 6;
    int x = v;
#pragma unroll
    for (int off = 1; off < 64; off <<= 1) {
        int t = __shfl_up(x, off, 64);
        if (lane >= off) x += t;
    }
    if (lane == 63) s_w[wv] = x;
    __syncthreads();
    if (tid < 16) {
        int y = s_w[tid];
#pragma unroll
        for (int off = 1; off < 16; off <<= 1) {
            int t = __shfl_up(y, off, 16);
            if (tid >= off) y += t;
        }
        s_w[tid] = y;
    }
    __syncthreads();
    int base = wv ? s_w[wv - 1] : 0;
    int tot  = s_w[15];
    __syncthreads();   // protect s_w reuse
    *total = tot;
    return base + x - v;   // exclusive prefix
}

// ---------------- Phase A: full coarsening, single block ----------------
// s_bc slots: 0=node 1=p 2=nbrCnt 3=hnCnt 4=orderBase 5=appendBase 6=finalBase 7=maxdeg 9=not64
__global__ __launch_bounds__(NT, 1)
void phaseA(const int* __restrict__ ei, int E0,
            int* __restrict__ U, int* __restrict__ V,
            unsigned int* __restrict__ BM,
            int* __restrict__ SLOT, int* __restrict__ NBR,
            int* __restrict__ OTH, int* __restrict__ PAIR,
            int* __restrict__ SEL, int* __restrict__ CNTS,
            int* __restrict__ NST, int* __restrict__ FIL, int* __restrict__ SC,
            float* __restrict__ out)
{
    __shared__ unsigned short s_order[NNODES];
    __shared__ unsigned char  s_vis[NNODES];
    __shared__ unsigned char  s_sel[NNODES];
    __shared__ unsigned int   s_hb[NNODES / 32];
    __shared__ unsigned short s_so[NNODES];     // selection order
    __shared__ unsigned short s_cnt[NNODES];    // counts per hub
    __shared__ unsigned int   s_nst[NNODES];    // nbr segment starts
    __shared__ int s_roff[NNODES];              // CSR row start
    __shared__ int s_rend[NNODES];              // CSR row end
    __shared__ int s_tmp[NNODES];               // deg / iter-0 stage / HnList / rank
    __shared__ int s_w[16];
    __shared__ int s_bc[16];

    const int tid = threadIdx.x;

    for (int i = tid; i < NNODES; i += NT) { s_vis[i] = 0; s_sel[i] = 0; s_tmp[i] = 0; }
    for (int i = tid; i < NNODES / 32; i += NT) s_hb[i] = 0;
    if (tid < 16) s_bc[tid] = 0;
    __syncthreads();

    // ---- detect int64 vs int32 edge buffer (high words all zero => int64) ----
    for (int i = tid; i < E0; i += NT)
        if (ei[2 * i + 1] != 0) s_bc[9] = 1;
    __syncthreads();
    const int is64 = !s_bc[9];

    // ---- copy edges + degree histogram (I+O) ----
    for (int e = tid; e < E0; e += NT) {
        int uu = ei[is64 ? 2 * e : e];
        int vv = ei[is64 ? 2 * (E0 + e) : (E0 + e)];
        U[e] = uu; V[e] = vv;
        atomicAdd(&s_tmp[uu], 1);
        atomicAdd(&s_tmp[vv], 1);
    }
    __syncthreads();
    for (int n = tid; n < NNODES; n += NT) atomicMax(&s_bc[7], s_tmp[n]);
    __syncthreads();
    const int maxd = s_bc[7];

    // ---- stable argsort by descending degree (counting placement) ----
    for (int d = maxd; d >= 0; --d) {
        int n0 = tid * 4;
        int f0 = (s_tmp[n0] == d), f1 = (s_tmp[n0 + 1] == d);
        int f2 = (s_tmp[n0 + 2] == d), f3 = (s_tmp[n0 + 3] == d);
        int tot;
        int off = blockScanExcl(f0 + f1 + f2 + f3, s_w, &tot);
        int idx = s_bc[4] + off;
        if (f0) s_order[idx++] = (unsigned short)n0;
        if (f1) s_order[idx++] = (unsigned short)(n0 + 1);
        if (f2) s_order[idx++] = (unsigned short)(n0 + 2);
        if (f3) s_order[idx++] = (unsigned short)(n0 + 3);
        __syncthreads();
        if (tid == 0) s_bc[4] += tot;
        __syncthreads();
    }

    // ================= iteration 0 (full-array scans) =================
    if (tid == 0) {
        int nd = s_order[0];
        s_bc[0] = nd; s_sel[nd] = 1; s_vis[nd] = 1;
        s_so[0] = (unsigned short)nd; s_nst[0] = 0;
    }
    __syncthreads();
    {
        const int node = s_bc[0];
        for (int e = tid; e < E0; e += NT) {
            int uu = U[e], vv = V[e];
            if (uu == node) {
                int w = vv; unsigned m = 1u << (w & 31);
                unsigned old = atomicOr(&s_hb[w >> 5], m);
                if (!(old & m)) { int i = atomicAdd(&s_bc[2], 1); s_tmp[i] = w; s_vis[w] = 1; }
            }
            if (vv == node) {
                int w = uu; unsigned m = 1u << (w & 31);
                unsigned old = atomicOr(&s_hb[w >> 5], m);
                if (!(old & m)) { int i = atomicAdd(&s_bc[2], 1); s_tmp[i] = w; s_vis[w] = 1; }
            }
        }
        __syncthreads();
        if (tid == 0) s_cnt[0] = (unsigned short)s_bc[2];
        // relabel Hn = H \ {node}
        for (int e = tid; e < E0; e += NT) {
            int uu = U[e];
            if (uu != node && ((s_hb[uu >> 5] >> (uu & 31)) & 1)) U[e] = node;
            int vv = V[e];
            if (vv != node && ((s_hb[vv >> 5] >> (vv & 31)) & 1)) V[e] = node;
        }
        __syncthreads();
    }

    // ---- symmetry append (only iteration ever needing it) ----
    for (int i = tid; i < (1 << 19); i += NT) BM[i] = 0u;
    __syncthreads();
    for (int e = tid; e < E0; e += NT) {
        int uu = U[e], vv = V[e];
        if (uu != vv) {
            unsigned code = ((unsigned)uu << 12) | (unsigned)vv;
            atomicOr(&BM[code >> 5], 1u << (code & 31));
        }
    }
    __syncthreads();
    for (int t = 0; t < E0; t += NT) {
        int e = t + tid, flag = 0, uu = 0, vv = 0;
        if (e < E0) {
            uu = U[e]; vv = V[e];
            if (uu != vv) {
                unsigned rc = ((unsigned)vv << 12) | (unsigned)uu;
                unsigned old = atomicOr(&BM[rc >> 5], 0u);   // L2 read (bypasses stale L1)
                flag = !((old >> (rc & 31)) & 1u);
            }
        }
        int tot;
        int off = blockScanExcl(flag, s_w, &tot);
        if (flag) { int r = s_bc[5] + off; U[E0 + r] = vv; V[E0 + r] = uu; }
        __syncthreads();
        if (tid == 0) s_bc[5] += tot;
        __syncthreads();
    }
    const int E1 = E0 + s_bc[5];

    // ---- build static CSR over alive arcs (bitmap region now reused as SLOT/NBR/OTH/PAIR) ----
    for (int n = tid; n < NNODES; n += NT) s_roff[n] = 0;
    __syncthreads();
    for (int e = tid; e < E1; e += NT) {
        int uu = U[e], vv = V[e];
        if (uu != vv) { atomicAdd(&s_roff[uu], 1); atomicAdd(&s_roff[vv], 1); }
    }
    __syncthreads();
    {
        int n0 = tid * 4;
        int c0 = s_roff[n0], c1 = s_roff[n0 + 1], c2 = s_roff[n0 + 2], c3 = s_roff[n0 + 3];
        int tot;
        int off = blockScanExcl(c0 + c1 + c2 + c3, s_w, &tot);
        int st = off;
        s_roff[n0] = st;     s_rend[n0] = st;     st += c0;
        s_roff[n0 + 1] = st; s_rend[n0 + 1] = st; st += c1;
        s_roff[n0 + 2] = st; s_rend[n0 + 2] = st; st += c2;
        s_roff[n0 + 3] = st; s_rend[n0 + 3] = st;
    }
    __syncthreads();
    for (int e = tid; e < E1; e += NT) {
        int uu = U[e], vv = V[e];
        if (uu != vv) {
            int p = atomicAdd(&s_rend[uu], 1);
            int q = atomicAdd(&s_rend[vv], 1);
            SLOT[p] = 2 * e;     SLOT[q] = 2 * e + 1;
            OTH[p]  = vv;        OTH[q]  = uu;
            PAIR[p] = q;         PAIR[q] = p;
        }
    }
    __syncthreads();
    {   // flush iter-0 staged H into global NBR; reset bitset
        const int cnt0 = s_bc[2];
        for (int i = tid; i < cnt0; i += NT) NBR[i] = s_tmp[i];
    }
    for (int i = tid; i < NNODES / 32; i += NT) s_hb[i] = 0;
    __syncthreads();

    // ================= main loop: CSR-driven iterations =================
    const int wv = tid >> 6, ln = tid & 63;
    int k = 1;
    for (;;) {
        if (tid == 0) {
            s_bc[3] = 0;                       // hnCnt
            int p = s_bc[1];
            while (p < NNODES && s_vis[s_order[p]]) p++;
            s_bc[1] = p;
            if (p < NNODES) {
                int nd = s_order[p];
                s_bc[0] = nd; s_sel[nd] = 1; s_vis[nd] = 1;
                s_so[k] = (unsigned short)nd;
                s_nst[k] = (unsigned)s_bc[2];
            }
        }
        __syncthreads();
        if (s_bc[1] >= NNODES) break;
        const int node = s_bc[0];
        const int rb = s_roff[node], re = s_rend[node];
        // ---- hub scan: one load level (OTH holds current other-endpoint) ----
        for (int s = rb + tid; s < re; s += NT) {
            int w = OTH[s];
            unsigned m = 1u << (w & 31);
            unsigned old = atomicOr(&s_hb[w >> 5], m);
            if (!(old & m)) {
                int i = atomicAdd(&s_bc[2], 1); NBR[i] = w; s_vis[w] = 1;
                if (!s_sel[w]) { int j = atomicAdd(&s_bc[3], 1); s_tmp[j] = w; }
            }
        }
        __syncthreads();
        if (tid == 0) s_cnt[k] = (unsigned short)(s_bc[2] - (int)s_nst[k]);
        // ---- relabel: wave-parallel over each Hn member's row ----
        const int hn = s_bc[3];
        for (int i = wv; i < hn; i += 16) {
            int h = s_tmp[i];
            int e0 = s_roff[h], e1 = s_rend[h];
            for (int s = e0 + ln; s < e1; s += 64) {
                int sl = SLOT[s]; int e = sl >> 1;
                if (sl & 1) V[e] = node; else U[e] = node;
                OTH[PAIR[s]] = node;   // twin slot sees the new label
            }
        }
        for (int i = tid; i < NNODES / 32; i += NT) s_hb[i] = 0;
        __syncthreads();
        k++;
    }
    const int K = k;

    // ---- dump metadata ----
    for (int i = tid; i < K; i += NT) {
        SEL[i] = (int)s_so[i]; CNTS[i] = (int)s_cnt[i]; NST[i] = (int)s_nst[i];
    }
    if (tid == 0) {
        SC[0] = K;
        int f = 0;
        for (int i = 0; i < K; i++) { if (s_cnt[i] > 0) f = i; FIL[i] = f; }
    }
    // ---- rank of each selected node among sorted(select) ----
    {
        int n0 = tid * 4;
        int r0 = s_sel[n0], r1 = s_sel[n0 + 1], r2 = s_sel[n0 + 2], r3 = s_sel[n0 + 3];
        int tot;
        int off = blockScanExcl(r0 + r1 + r2 + r3, s_w, &tot);
        int st = off;
        s_tmp[n0] = st;     st += r0;
        s_tmp[n0 + 1] = st; st += r1;
        s_tmp[n0 + 2] = st; st += r2;
        s_tmp[n0 + 3] = st;
    }
    __syncthreads();
    // ---- final stable compaction + remap + write ei_out (float32) ----
    const size_t obase = (size_t)K * 8192;
    for (int t = 0; t < E1; t += NT) {
        int e = t + tid, flag = 0, uu = 0, vv = 0;
        if (e < E1) { uu = U[e]; vv = V[e]; flag = (uu != vv); }
        int tot;
        int off = blockScanExcl(flag, s_w, &tot);
        if (flag) {
            int r = s_bc[6] + off;
            out[obase + (size_t)r] = (float)s_tmp[uu];
            SLOT[r] = s_tmp[vv];
        }
        __syncthreads();
        if (tid == 0) s_bc[6] += tot;
        __syncthreads();
    }
    const int Ef = s_bc[6];
    if (tid == 0) SC[1] = Ef;
    for (int r = tid; r < Ef; r += NT)
        out[obase + (size_t)Ef + (size_t)r] = (float)SLOT[r];
}

// ---------------- Phase B: END rows (Dv | mean) with fill indirection ----------------
__global__ __launch_bounds__(256, 4)
void phaseB(const float* __restrict__ x,
            const float* __restrict__ W1, const float* __restrict__ W2,
            const float* __restrict__ B1, const float* __restrict__ B2,
            const int* __restrict__ NBR, const int* __restrict__ SEL,
            const int* __restrict__ CNTS, const int* __restrict__ NST,
            const int* __restrict__ FIL, const int* __restrict__ SC,
            float* __restrict__ out)
{
    const int K = SC[0];
    const int k = blockIdx.x;
    if (k >= K) return;
    const int kk   = FIL[k];
    const int node = SEL[kk];
    const int cnt  = CNTS[kk];
    const int st   = NST[kk];
    const int tid  = threadIdx.x;
    const float4* x4 = (const float4*)x;

    float4 acc[4];
#pragma unroll
    for (int j = 0; j < 4; j++) acc[j] = make_float4(0.f, 0.f, 0.f, 0.f);

    for (int r = 0; r < cnt; ++r) {
        const float4* row = x4 + (size_t)NBR[st + r] * 1024;
#pragma unroll
        for (int j = 0; j < 4; j++) {
            float4 t = row[tid + j * 256];
            acc[j].x += t.x; acc[j].y += t.y; acc[j].z += t.z; acc[j].w += t.w;
        }
    }

    const float fc  = (float)cnt;
    const float inv = 1.0f / (float)(cnt > 1 ? cnt : 1);
    const float4* xr = x4 + (size_t)node * 1024;
    float4* o4 = (float4*)(out + (size_t)k * 8192);

#pragma unroll
    for (int j = 0; j < 4; j++) {
        int c = tid + j * 256;
        float4 w1 = ((const float4*)W1)[c], b1 = ((const float4*)B1)[c];
        float4 w2 = ((const float4*)W2)[c], b2 = ((const float4*)B2)[c];
        float4 xv = xr[c];
        float4 pd, pm;
        pd.x = xv.x * w2.x + b2.x;
        pd.y = xv.y * w2.y + b2.y;
        pd.z = xv.z * w2.z + b2.z;
        pd.w = xv.w * w2.w + b2.w;
        pm.x = (acc[j].x * w1.x + fc * b1.x) * inv;
        pm.y = (acc[j].y * w1.y + fc * b1.y) * inv;
        pm.z = (acc[j].z * w1.z + fc * b1.z) * inv;
        pm.w = (acc[j].w * w1.w + fc * b1.w) * inv;
        o4[c] = pd;
        o4[1024 + c] = pm;
    }
}

extern "C" void kernel_launch(void* const* d_in, const int* in_sizes, int n_in,
                              void* d_out, int out_size, void* d_ws, size_t ws_size,
                              hipStream_t stream)
{
    const float* x  = (const float*)d_in[0];
    const int*   ei = (const int*)d_in[1];
    const float* W1 = (const float*)d_in[2];
    const float* W2 = (const float*)d_in[3];
    const float* B1 = (const float*)d_in[4];
    const float* B2 = (const float*)d_in[5];
    const int E0 = in_sizes[1] / 2;

    char* w = (char*)d_ws;
    int* U = (int*)w;                         // [ECAP]
    int* V = U + ECAP;                        // [ECAP]
    unsigned int* BM = (unsigned int*)(V + ECAP);   // 2 MB bitmap (iter-0 only)
    int* SLOT = (int*)BM;                     // [2*ECAP] (reuses bitmap region)
    int* NBR  = SLOT + 2 * ECAP;              // [2*ECAP]
    int* OTH  = NBR  + 2 * ECAP;              // [2*ECAP]
    int* PAIR = OTH  + 2 * ECAP;              // [2*ECAP]  (4 x 512KB = the 2MB region)
    char* meta = (char*)BM + (2u << 20);
    int* SEL  = (int*)meta;
    int* CNTS = SEL + NNODES;
    int* NST  = CNTS + NNODES;
    int* FIL  = NST + NNODES;
    int* SC   = FIL + NNODES;
    float* out = (float*)d_out;

    hipLaunchKernelGGL(phaseA, dim3(1), dim3(NT), 0, stream,
                       ei, E0, U, V, BM, SLOT, NBR, OTH, PAIR,
                       SEL, CNTS, NST, FIL, SC, out);
    hipLaunchKernelGGL(phaseB, dim3(NNODES), dim3(256), 0, stream,
                       x, W1, W2, B1, B2, NBR, SEL, CNTS, NST, FIL, SC, out);
}

// Round 4
// 972.486 us; speedup vs baseline: 2.9115x; 1.8004x over previous
//
#include <hip/hip_runtime.h>
#include <hip/hip_bf16.h>

#define NT 1024
#define NNODES 4096
#define ECAP 65536   // max arcs after iteration-1 symmetrization (E0 <= 32768)

// ---------------- block-wide exclusive scan over NT=1024 values ----------------
__device__ __forceinline__ int blockScanExcl(int v, int* s_w, int* total) {
    const int tid  = threadIdx.x;
    const int lane = tid & 63;
    const int wv   = tid >> 6;
    int x = v;
#pragma unroll
    for (int off = 1; off < 64; off <<= 1) {
        int t = __shfl_up(x, off, 64);
        if (lane >= off) x += t;
    }
    if (lane == 63) s_w[wv] = x;
    __syncthreads();
    if (tid < 16) {
        int y = s_w[tid];
#pragma unroll
        for (int off = 1; off < 16; off <<= 1) {
            int t = __shfl_up(y, off, 16);
            if (tid >= off) y += t;
        }
        s_w[tid] = y;
    }
    __syncthreads();
    int base = wv ? s_w[wv - 1] : 0;
    int tot  = s_w[15];
    __syncthreads();   // protect s_w reuse
    *total = tot;
    return base + x - v;   // exclusive prefix
}

// ---------------- Phase A: full coarsening, single block ----------------
// s_bc slots: 0=node 1=unused 2=nbrCnt 3=unused 4=orderBase 5=appendBase 6=finalBase 7=maxdeg 9=not64
__global__ __launch_bounds__(NT, 1)
void phaseA(const int* __restrict__ ei, int E0,
            int* __restrict__ U, int* __restrict__ V,
            unsigned int* __restrict__ BM,
            int* __restrict__ NBR, int* __restrict__ OTH, int* __restrict__ TMP,
            int* __restrict__ SEL, int* __restrict__ CNTS,
            int* __restrict__ NST, int* __restrict__ FIL, int* __restrict__ SC,
            float* __restrict__ out)
{
    __shared__ unsigned short s_order[NNODES];
    __shared__ unsigned char  s_vis[NNODES];
    __shared__ unsigned char  s_sel[NNODES];
    __shared__ unsigned int   s_hb[NNODES / 32];
    __shared__ unsigned short s_so[NNODES];       // selection order
    __shared__ unsigned int   s_nst[NNODES + 1];  // nbr segment starts (cumulative)
    __shared__ int s_roff[NNODES];                // CSR row start
    __shared__ int s_rend[NNODES];                // CSR row end
    __shared__ int s_tmp[NNODES];                 // deg / iter-0 stage / rank
    __shared__ unsigned short s_lab[NNODES];      // lazy label (chain length <= 1)
    __shared__ int s_stamp[NNODES];               // per-iteration dedup epoch
    __shared__ int s_w[16];
    __shared__ int s_bc[16];

    const int tid = threadIdx.x;
    const int ln  = tid & 63;

    for (int i = tid; i < NNODES; i += NT) {
        s_vis[i] = 0; s_sel[i] = 0; s_tmp[i] = 0; s_stamp[i] = 0;
    }
    for (int i = tid; i < NNODES / 32; i += NT) s_hb[i] = 0;
    if (tid < 16) s_bc[tid] = 0;
    __syncthreads();

    // ---- detect int64 vs int32 edge buffer (high words all zero => int64) ----
    for (int i = tid; i < E0; i += NT)
        if (ei[2 * i + 1] != 0) s_bc[9] = 1;
    __syncthreads();
    const int is64 = !s_bc[9];

    // ---- copy edges + degree histogram (I+O) ----
    for (int e = tid; e < E0; e += NT) {
        int uu = ei[is64 ? 2 * e : e];
        int vv = ei[is64 ? 2 * (E0 + e) : (E0 + e)];
        U[e] = uu; V[e] = vv;
        atomicAdd(&s_tmp[uu], 1);
        atomicAdd(&s_tmp[vv], 1);
    }
    __syncthreads();
    for (int n = tid; n < NNODES; n += NT) atomicMax(&s_bc[7], s_tmp[n]);
    __syncthreads();
    const int maxd = s_bc[7];

    // ---- stable argsort by descending degree (counting placement) ----
    for (int d = maxd; d >= 0; --d) {
        int n0 = tid * 4;
        int f0 = (s_tmp[n0] == d), f1 = (s_tmp[n0 + 1] == d);
        int f2 = (s_tmp[n0 + 2] == d), f3 = (s_tmp[n0 + 3] == d);
        int tot;
        int off = blockScanExcl(f0 + f1 + f2 + f3, s_w, &tot);
        int idx = s_bc[4] + off;
        if (f0) s_order[idx++] = (unsigned short)n0;
        if (f1) s_order[idx++] = (unsigned short)(n0 + 1);
        if (f2) s_order[idx++] = (unsigned short)(n0 + 2);
        if (f3) s_order[idx++] = (unsigned short)(n0 + 3);
        __syncthreads();
        if (tid == 0) s_bc[4] += tot;
        __syncthreads();
    }

    // ================= iteration 0 (full-array scans, eager relabel) =================
    if (tid == 0) {
        int nd = s_order[0];
        s_bc[0] = nd; s_sel[nd] = 1; s_vis[nd] = 1;
        s_so[0] = (unsigned short)nd; s_nst[0] = 0;
    }
    __syncthreads();
    {
        const int node = s_bc[0];
        for (int e = tid; e < E0; e += NT) {
            int uu = U[e], vv = V[e];
            if (uu == node) {
                int w = vv; unsigned m = 1u << (w & 31);
                unsigned old = atomicOr(&s_hb[w >> 5], m);
                if (!(old & m)) { int i = atomicAdd(&s_bc[2], 1); s_tmp[i] = w; s_vis[w] = 1; }
            }
            if (vv == node) {
                int w = uu; unsigned m = 1u << (w & 31);
                unsigned old = atomicOr(&s_hb[w >> 5], m);
                if (!(old & m)) { int i = atomicAdd(&s_bc[2], 1); s_tmp[i] = w; s_vis[w] = 1; }
            }
        }
        __syncthreads();
        // eager relabel Hn = H \ {node} (U/V frozen after this iteration)
        for (int e = tid; e < E0; e += NT) {
            int uu = U[e];
            if (uu != node && ((s_hb[uu >> 5] >> (uu & 31)) & 1)) U[e] = node;
            int vv = V[e];
            if (vv != node && ((s_hb[vv >> 5] >> (vv & 31)) & 1)) V[e] = node;
        }
        __syncthreads();
    }

    // ---- symmetry append (only iteration ever needing it) ----
    for (int i = tid; i < (1 << 19); i += NT) BM[i] = 0u;
    __syncthreads();
    for (int e = tid; e < E0; e += NT) {
        int uu = U[e], vv = V[e];
        if (uu != vv) {
            unsigned code = ((unsigned)uu << 12) | (unsigned)vv;
            atomicOr(&BM[code >> 5], 1u << (code & 31));
        }
    }
    __syncthreads();
    for (int t = 0; t < E0; t += NT) {
        int e = t + tid, flag = 0, uu = 0, vv = 0;
        if (e < E0) {
            uu = U[e]; vv = V[e];
            if (uu != vv) {
                unsigned rc = ((unsigned)vv << 12) | (unsigned)uu;
                unsigned old = atomicOr(&BM[rc >> 5], 0u);   // L2 read (bypasses stale L1)
                flag = !((old >> (rc & 31)) & 1u);
            }
        }
        int tot;
        int off = blockScanExcl(flag, s_w, &tot);
        if (flag) { int r = s_bc[5] + off; U[E0 + r] = vv; V[E0 + r] = uu; }
        __syncthreads();
        if (tid == 0) s_bc[5] += tot;
        __syncthreads();
    }
    const int E1 = E0 + s_bc[5];

    // ---- build static CSR (other-endpoint only; BM region reused as OTH/NBR/TMP) ----
    for (int n = tid; n < NNODES; n += NT) s_roff[n] = 0;
    __syncthreads();
    for (int e = tid; e < E1; e += NT) {
        int uu = U[e], vv = V[e];
        if (uu != vv) { atomicAdd(&s_roff[uu], 1); atomicAdd(&s_roff[vv], 1); }
    }
    __syncthreads();
    {
        int n0 = tid * 4;
        int c0 = s_roff[n0], c1 = s_roff[n0 + 1], c2 = s_roff[n0 + 2], c3 = s_roff[n0 + 3];
        int tot;
        int off = blockScanExcl(c0 + c1 + c2 + c3, s_w, &tot);
        int st = off;
        s_roff[n0] = st;     s_rend[n0] = st;     st += c0;
        s_roff[n0 + 1] = st; s_rend[n0 + 1] = st; st += c1;
        s_roff[n0 + 2] = st; s_rend[n0 + 2] = st; st += c2;
        s_roff[n0 + 3] = st; s_rend[n0 + 3] = st;
    }
    __syncthreads();
    for (int e = tid; e < E1; e += NT) {
        int uu = U[e], vv = V[e];
        if (uu != vv) {
            int p = atomicAdd(&s_rend[uu], 1);
            int q = atomicAdd(&s_rend[vv], 1);
            OTH[p] = vv; OTH[q] = uu;
        }
    }
    __syncthreads();
    {   // flush iter-0 staged H into global NBR; init lazy labels to identity
        const int cnt0 = s_bc[2];
        for (int i = tid; i < cnt0; i += NT) NBR[i] = s_tmp[i];
    }
    for (int i = tid; i < NNODES; i += NT) s_lab[i] = (unsigned short)i;
    __syncthreads();

    // ================= main loop: 1 barrier/iter, lazy labels, epoch stamps =================
    int p = 0, k = 1;
    for (;;) {
        __syncthreads();                       // iteration boundary
        if (tid == 0) s_nst[k] = (unsigned)s_bc[2];   // segment start (stable: see margin arg)
        // ---- selection: every wave ballots the same 64-wide window (deterministic:
        //      vis flags are monotone and all unvisited entries sit at >= sel) ----
        int node = -1;
        for (;;) {
            if (p >= NNODES) break;
            int cand = (p + ln < NNODES) ? (int)s_order[p + ln] : -1;
            int unvis = (cand >= 0) && (!s_vis[cand]);
            unsigned long long bal = __ballot(unvis);
            if (bal != 0ull) {
                int sel = __ffsll(bal) - 1;
                node = __shfl(cand, sel, 64);
                p += sel + 1;                  // window prefix is permanently visited
                break;
            }
            p += 64;
        }
        if (node < 0) break;                   // uniform
        if (tid == 0) { s_sel[node] = 1; s_so[k] = (unsigned short)node; }
        // ---- hub scan: static row + lazy label resolve + epoch-stamp dedup ----
        const int rb = s_roff[node], re = s_rend[node];
        for (int s = rb + tid; s < re; s += NT) {
            int w = (int)s_lab[OTH[s]];
            if (w == node) continue;           // racy same-iteration relabel: already counted
            int old = atomicMax(&s_stamp[w], k);
            if (old < k) {
                int i = atomicAdd(&s_bc[2], 1);
                NBR[i] = w;
                s_vis[w] = 1;
                if (!s_sel[w]) s_lab[w] = (unsigned short)node;   // absorb (chain <= 1)
            }
        }
        k++;
    }
    const int K = k;   // s_nst[K] was written on the failing entry
    __syncthreads();

    // ---- dump metadata ----
    for (int i = tid; i < K; i += NT) {
        SEL[i]  = (int)s_so[i];
        CNTS[i] = (int)(s_nst[i + 1] - s_nst[i]);
        NST[i]  = (int)s_nst[i];
    }
    if (tid == 0) {
        SC[0] = K;
        int f = 0;
        for (int i = 0; i < K; i++) { if (s_nst[i + 1] > s_nst[i]) f = i; FIL[i] = f; }
    }
    // ---- rank of each selected node among sorted(select) ----
    {
        int n0 = tid * 4;
        int r0 = s_sel[n0], r1 = s_sel[n0 + 1], r2 = s_sel[n0 + 2], r3 = s_sel[n0 + 3];
        int tot;
        int off = blockScanExcl(r0 + r1 + r2 + r3, s_w, &tot);
        int st = off;
        s_tmp[n0] = st;     st += r0;
        s_tmp[n0 + 1] = st; st += r1;
        s_tmp[n0 + 2] = st; st += r2;
        s_tmp[n0 + 3] = st;
    }
    __syncthreads();
    // ---- final stable compaction: resolve lazy labels + remap + write ei_out ----
    const size_t obase = (size_t)K * 8192;
    for (int t = 0; t < E1; t += NT) {
        int e = t + tid, flag = 0, ru = 0, rv = 0;
        if (e < E1) {
            int uu = (int)s_lab[U[e]], vv = (int)s_lab[V[e]];
            if (uu != vv) { flag = 1; ru = s_tmp[uu]; rv = s_tmp[vv]; }
        }
        int tot;
        int off = blockScanExcl(flag, s_w, &tot);
        if (flag) {
            int r = s_bc[6] + off;
            out[obase + (size_t)r] = (float)ru;
            TMP[r] = rv;
        }
        __syncthreads();
        if (tid == 0) s_bc[6] += tot;
        __syncthreads();
    }
    const int Ef = s_bc[6];
    if (tid == 0) SC[1] = Ef;
    for (int r = tid; r < Ef; r += NT)
        out[obase + (size_t)Ef + (size_t)r] = (float)TMP[r];
}

// ---------------- Phase B: END rows (Dv | mean) with fill indirection ----------------
__global__ __launch_bounds__(256, 4)
void phaseB(const float* __restrict__ x,
            const float* __restrict__ W1, const float* __restrict__ W2,
            const float* __restrict__ B1, const float* __restrict__ B2,
            const int* __restrict__ NBR, const int* __restrict__ SEL,
            const int* __restrict__ CNTS, const int* __restrict__ NST,
            const int* __restrict__ FIL, const int* __restrict__ SC,
            float* __restrict__ out)
{
    const int K = SC[0];
    const int k = blockIdx.x;
    if (k >= K) return;
    const int kk   = FIL[k];
    const int node = SEL[kk];
    const int cnt  = CNTS[kk];
    const int st   = NST[kk];
    const int tid  = threadIdx.x;
    const float4* x4 = (const float4*)x;

    float4 acc[4];
#pragma unroll
    for (int j = 0; j < 4; j++) acc[j] = make_float4(0.f, 0.f, 0.f, 0.f);

    for (int r = 0; r < cnt; ++r) {
        const float4* row = x4 + (size_t)NBR[st + r] * 1024;
#pragma unroll
        for (int j = 0; j < 4; j++) {
            float4 t = row[tid + j * 256];
            acc[j].x += t.x; acc[j].y += t.y; acc[j].z += t.z; acc[j].w += t.w;
        }
    }

    const float fc  = (float)cnt;
    const float inv = 1.0f / (float)(cnt > 1 ? cnt : 1);
    const float4* xr = x4 + (size_t)node * 1024;
    float4* o4 = (float4*)(out + (size_t)k * 8192);

#pragma unroll
    for (int j = 0; j < 4; j++) {
        int c = tid + j * 256;
        float4 w1 = ((const float4*)W1)[c], b1 = ((const float4*)B1)[c];
        float4 w2 = ((const float4*)W2)[c], b2 = ((const float4*)B2)[c];
        float4 xv = xr[c];
        float4 pd, pm;
        pd.x = xv.x * w2.x + b2.x;
        pd.y = xv.y * w2.y + b2.y;
        pd.z = xv.z * w2.z + b2.z;
        pd.w = xv.w * w2.w + b2.w;
        pm.x = (acc[j].x * w1.x + fc * b1.x) * inv;
        pm.y = (acc[j].y * w1.y + fc * b1.y) * inv;
        pm.z = (acc[j].z * w1.z + fc * b1.z) * inv;
        pm.w = (acc[j].w * w1.w + fc * b1.w) * inv;
        o4[c] = pd;
        o4[1024 + c] = pm;
    }
}

extern "C" void kernel_launch(void* const* d_in, const int* in_sizes, int n_in,
                              void* d_out, int out_size, void* d_ws, size_t ws_size,
                              hipStream_t stream)
{
    const float* x  = (const float*)d_in[0];
    const int*   ei = (const int*)d_in[1];
    const float* W1 = (const float*)d_in[2];
    const float* W2 = (const float*)d_in[3];
    const float* B1 = (const float*)d_in[4];
    const float* B2 = (const float*)d_in[5];
    const int E0 = in_sizes[1] / 2;

    char* w = (char*)d_ws;
    int* U = (int*)w;                         // [ECAP]
    int* V = U + ECAP;                        // [ECAP]
    unsigned int* BM = (unsigned int*)(V + ECAP);   // 2 MB bitmap (iter-0 only)
    int* OTH = (int*)BM;                      // [2*ECAP] static CSR other-endpoint
    int* NBR = OTH + 2 * ECAP;                // [2*ECAP]
    int* TMP = NBR + 2 * ECAP;                // [2*ECAP] final-pass scratch
    char* meta = (char*)BM + (2u << 20);
    int* SEL  = (int*)meta;
    int* CNTS = SEL + NNODES;
    int* NST  = CNTS + NNODES;
    int* FIL  = NST + NNODES;
    int* SC   = FIL + NNODES;
    float* out = (float*)d_out;

    hipLaunchKernelGGL(phaseA, dim3(1), dim3(NT), 0, stream,
                       ei, E0, U, V, BM, NBR, OTH, TMP,
                       SEL, CNTS, NST, FIL, SC, out);
    hipLaunchKernelGGL(phaseB, dim3(NNODES), dim3(256), 0, stream,
                       x, W1, W2, B1, B2, NBR, SEL, CNTS, NST, FIL, SC, out);
}